// Round 7
// baseline (132.367 us; speedup 1.0000x reference)
//
#include <hip/hip_runtime.h>

typedef __bf16 bf16_t;
typedef __bf16 bf16x8 __attribute__((ext_vector_type(8)));
typedef __bf16 bf16x4 __attribute__((ext_vector_type(4)));
typedef float f32x4 __attribute__((ext_vector_type(4)));

__device__ __forceinline__ void async16(const void* g, void* l) {
  __builtin_amdgcn_global_load_lds(
      (const __attribute__((address_space(1))) unsigned int*)g,
      (__attribute__((address_space(3))) unsigned int*)l,
      16, 0, 0);
}

__device__ __forceinline__ bf16x8 cvt8(const float4 a, const float4 b) {
  bf16x8 v;
  v[0] = (bf16_t)a.x; v[1] = (bf16_t)a.y; v[2] = (bf16_t)a.z; v[3] = (bf16_t)a.w;
  v[4] = (bf16_t)b.x; v[5] = (bf16_t)b.y; v[6] = (bf16_t)b.z; v[7] = (bf16_t)b.w;
  return v;
}

// ---------------------------------------------------------------------------
// Fused prep for Bcat (512 x 1024 bf16):
//   blocks 0..255   : convert proj_R (256x1024 f32) -> Bcat rows 256..511
//   blocks 256..511 : LDS-tiled transpose proj_L (1024x256 f32) -> rows 0..255
// ---------------------------------------------------------------------------
__global__ void prep_Bcat(const float* __restrict__ projL,
                          const float* __restrict__ projR,
                          bf16_t* __restrict__ Bcat) {
  const int t = threadIdx.x;
  if (blockIdx.x < 256) {
    int i = blockIdx.x * 256 + t;
    float4 v = ((const float4*)projR)[i];
    bf16x4 o;
    o[0] = (bf16_t)v.x; o[1] = (bf16_t)v.y; o[2] = (bf16_t)v.z; o[3] = (bf16_t)v.w;
    ((bf16x4*)(Bcat + (long)256 * 1024))[i] = o;
  } else {
    __shared__ float tile[32][33];
    const int bb = blockIdx.x - 256;
    const int n0 = (bb & 7) * 32;   // col block in projL (N=256)
    const int k0 = (bb >> 3) * 32;  // row block in projL (K=1024)
    const int tx = t & 31;
    const int ty = t >> 5;  // 0..7
#pragma unroll
    for (int i = 0; i < 32; i += 8)
      tile[ty + i][tx] = projL[(long)(k0 + ty + i) * 256 + n0 + tx];
    __syncthreads();
#pragma unroll
    for (int i = 0; i < 32; i += 8)
      Bcat[(long)(n0 + ty + i) * 1024 + k0 + tx] = (bf16_t)tile[tx][ty + i];
  }
}

// ---------------------------------------------------------------------------
// GEMM1 (A DIRECT-TO-REGISTER, no A-LDS path):
//   LR(8192x512 bf16) = batch(8192x1024 f32) @ Bcat(512x1024 bf16)^T
// 64x128 tile, 512 blocks -> 2 blocks/CU. BK=128, 8 steps.
// A: each wave loads its MFMA A-fragments straight from global f32 (element-
// identical to the old As-LDS read: row tm+wr+i*16+l15, k k0+kc*32+quad*8),
// cvt to bf16 in-reg. Eliminates 4 ds_write + 8 ds_read + As buffer per step.
// 2x A read-amplification (waves 0/1 == 2/3 rows) is absorbed by L1/L2.
// B: async16 into a TRUE double buffer. Each buffer = 4 kc-subtiles x 4096
// elem = 16384 elem = 32 KB  [R6 BUG: stride was 8192 -> buffers aliased].
// Total LDS 64 KB -> still 2 blocks/CU. Schedule per step: issue B-asyncs
// (s+1 -> nb) at step top -> A-loads + cvt + 32 MFMA (~300+ cy) -> ONE
// barrier, whose vmcnt(0) drain finds the asyncs long since landed.
// XCD swizzle: tm = bx&127, tn = bx>>7; A-row-tile sharers are 128 apart
// (128 % 8 == 0 -> same XCD) -> A re-reads hit local L2.
// ---------------------------------------------------------------------------
__global__ __launch_bounds__(256, 2) void gemm1_fusedA(
    const float* __restrict__ batch, const bf16_t* __restrict__ Bcat,
    bf16_t* __restrict__ LR) {
  const int bx = blockIdx.x;
  const int tm = (bx & 127) * 64;  // M tile (8192/64 = 128)
  const int tn = (bx >> 7) * 128;  // N tile (512/128 = 4)

  // Bs[buf][kc][128][32] : per buf 4*4096 = 16384 elem (32 KB); 2 bufs.
  __shared__ __attribute__((aligned(16))) bf16_t Bs[2 * 16384];

  const int t = threadIdx.x;
  const int lane = t & 63;
  const int quad = lane >> 4;
  const int l15 = lane & 15;
  const int wave = t >> 6;
  const int wr = (wave >> 1) * 32;  // 0 / 32  (M)
  const int wc = (wave & 1) * 64;   // 0 / 64  (N)

  // B staging (legal async16 map): row rS = t>>2 (0..63), 16B slot (t&3)*8;
  // LDS dest = wave-uniform base + t*16B. Second async per kc covers rows
  // 64..127 (+2048 elem).
  const int rS = t >> 2;
  const int cS = (t & 3) * 8;
  const bf16_t* gB = Bcat + (long)(tn + rS) * 1024 + cS;

  // A direct-fragment base: row tm+wr+l15 (i adds 16 rows), col quad*8
  const float* gA = batch + (long)(tm + wr + l15) * 1024 + quad * 8;

  f32x4 acc[2][4];
#pragma unroll
  for (int i = 0; i < 2; ++i)
#pragma unroll
    for (int j = 0; j < 4; ++j)
      acc[i][j] = (f32x4){0.f, 0.f, 0.f, 0.f};

  // ---- prologue: B-async16(step 0) -> buf 0 ----
#pragma unroll
  for (int kc = 0; kc < 4; ++kc) {
    async16(gB + kc * 32, Bs + kc * 4096 + t * 8);
    async16(gB + kc * 32 + (long)64 * 1024, Bs + kc * 4096 + 2048 + t * 8);
  }
  __syncthreads();

  for (int s = 0; s < 8; ++s) {  // K=1024, BK=128
    const int buf = s & 1;
    const int nb = buf ^ 1;
    const int k0 = s * 128;
    // issue B asyncs for s+1 into the other buffer (drained at the barrier
    // BELOW, after the full A-load+cvt+MFMA block = enough latency cover)
    if (s < 7) {
#pragma unroll
      for (int kc = 0; kc < 4; ++kc) {
        async16(gB + k0 + 128 + kc * 32, Bs + nb * 16384 + kc * 4096 + t * 8);
        async16(gB + k0 + 128 + kc * 32 + (long)64 * 1024,
                Bs + nb * 16384 + kc * 4096 + 2048 + t * 8);
      }
    }
    // A fragments: 16 independent float4 loads (compiler hoists issues early)
    float4 a0[4][2], a1[4][2];  // [kc][half] for row-blocks i=0, i=1
#pragma unroll
    for (int kc = 0; kc < 4; ++kc) {
      const float* p0 = gA + k0 + kc * 32;
      a0[kc][0] = *(const float4*)p0;
      a0[kc][1] = *(const float4*)(p0 + 4);
      const float* p1 = p0 + (long)16 * 1024;
      a1[kc][0] = *(const float4*)p1;
      a1[kc][1] = *(const float4*)(p1 + 4);
    }
#pragma unroll
    for (int kc = 0; kc < 4; ++kc) {
      bf16x8 af[2], bv[4];
      af[0] = cvt8(a0[kc][0], a0[kc][1]);
      af[1] = cvt8(a1[kc][0], a1[kc][1]);
      const bf16_t* Bk = Bs + buf * 16384 + kc * 4096;
#pragma unroll
      for (int j = 0; j < 4; ++j)
        bv[j] = *(const bf16x8*)(Bk + (wc + j * 16 + l15) * 32 + quad * 8);
#pragma unroll
      for (int i = 0; i < 2; ++i)
#pragma unroll
        for (int j = 0; j < 4; ++j)
          acc[i][j] = __builtin_amdgcn_mfma_f32_16x16x32_bf16(af[i], bv[j],
                                                              acc[i][j], 0, 0, 0);
    }
    __syncthreads();  // one barrier/step: aligns buf swap, drains s+1 asyncs
  }

  // Epilogue -> LR bf16 (ldc=512). C/D: col = lane&15, row = quad*4 + reg
#pragma unroll
  for (int i = 0; i < 2; ++i) {
    const int r0 = tm + wr + i * 16 + quad * 4;
#pragma unroll
    for (int j = 0; j < 4; ++j) {
      const int c0 = tn + wc + j * 16 + l15;
#pragma unroll
      for (int r = 0; r < 4; ++r)
        LR[(long)(r0 + r) * 512 + c0] = (bf16_t)acc[i][j][r];
    }
  }
}

// ---------------------------------------------------------------------------
// GEMM2 [R1's known-good form]:
// out[b](1024x1024 f32) = left[b](1024x256) @ right[b](1024x256)^T + bias
// left = LR[b] cols 0..255, right = LR[b] cols 256..511 (ld=512, bf16).
// 128x128 tile; K=256 as BK=64 x 4 steps, double-buffered
// (stage s+1 || compute s, one barrier per step). LDS 64 KB -> 2 blocks/CU.
// Flat 512-block grid, BATCH-to-XCD pinning: b = bx&7, tile = bx>>3 -> each
// batch's 1 MB LR slice is fetched once into one XCD's L2 and re-read there.
// ---------------------------------------------------------------------------
__global__ __launch_bounds__(256, 2) void gemm2(const bf16_t* __restrict__ LR,
                                                float* __restrict__ out,
                                                const float* __restrict__ bias) {
  const int bx = blockIdx.x;
  const int bz = bx & 7;         // batch -> XCD
  const int tile = bx >> 3;      // 0..63
  const int tm = (tile & 7) * 128;   // row tile (i)
  const int tn = (tile >> 3) * 128;  // col tile (j)
  const bf16_t* LRb = LR + (long)bz * 1024 * 512;

  // [buf][kc][128 rows][32 cols] bf16 ; buf stride 8192, kc stride 4096
  __shared__ __attribute__((aligned(16))) bf16_t As[2 * 8192];
  __shared__ __attribute__((aligned(16))) bf16_t Bs[2 * 8192];

  const int t = threadIdx.x;
  const int lane = t & 63;
  const int quad = lane >> 4;
  const int l15 = lane & 15;
  const int wave = t >> 6;
  const int wr = (wave >> 1) * 64;
  const int wc = (wave & 1) * 64;

  const int rS = t >> 2;          // 0..63
  const int cS = (t & 3) * 8;     // 0,8,16,24
  const bf16_t* gA = LRb + (long)(tm + rS) * 512 + cS;        // left
  const bf16_t* gB = LRb + (long)(tn + rS) * 512 + 256 + cS;  // right

  f32x4 acc[4][4];
#pragma unroll
  for (int i = 0; i < 4; ++i)
#pragma unroll
    for (int j = 0; j < 4; ++j)
      acc[i][j] = (f32x4){0.f, 0.f, 0.f, 0.f};

  // stage BK=64 slice s into buffer buf: 8 async16/thread (A:4, B:4)
  auto STAGE = [&](int buf, int s) {
    const int k0 = s * 64;
    bf16_t* dA = As + buf * 8192 + t * 8;  // t*8 == (t>>2)*32 + (t&3)*8
    bf16_t* dB = Bs + buf * 8192 + t * 8;
#pragma unroll
    for (int kc = 0; kc < 2; ++kc) {
      const int ko = k0 + kc * 32;
      async16(gA + ko, dA + kc * 4096);
      async16(gA + ko + (long)64 * 512, dA + kc * 4096 + 2048);
      async16(gB + ko, dB + kc * 4096);
      async16(gB + ko + (long)64 * 512, dB + kc * 4096 + 2048);
    }
  };

  STAGE(0, 0);
  __syncthreads();  // drains prologue async16

#pragma unroll
  for (int s = 0; s < 4; ++s) {  // K=256, BK=64
    if (s < 3) STAGE((s + 1) & 1, s + 1);  // prefetch into other buffer
    const bf16_t* Ab = As + (s & 1) * 8192;
    const bf16_t* Bb = Bs + (s & 1) * 8192;
#pragma unroll
    for (int kc = 0; kc < 2; ++kc) {
      const bf16_t* Ak = Ab + kc * 4096;
      const bf16_t* Bk = Bb + kc * 4096;
      bf16x8 af[4], bv[4];
#pragma unroll
      for (int i = 0; i < 4; ++i)
        af[i] = *(const bf16x8*)(Ak + (wr + i * 16 + l15) * 32 + quad * 8);
#pragma unroll
      for (int j = 0; j < 4; ++j)
        bv[j] = *(const bf16x8*)(Bk + (wc + j * 16 + l15) * 32 + quad * 8);
#pragma unroll
      for (int i = 0; i < 4; ++i)
#pragma unroll
        for (int j = 0; j < 4; ++j)
          acc[i][j] = __builtin_amdgcn_mfma_f32_16x16x32_bf16(af[i], bv[j],
                                                              acc[i][j], 0, 0, 0);
    }
    if (s < 3) __syncthreads();  // drains prefetch; protects buf reuse
  }

  float* C = out + (long)bz * 1024 * 1024;
  const float bvadd = bias[0];
#pragma unroll
  for (int i = 0; i < 4; ++i) {
    const int r0 = tm + wr + i * 16 + quad * 4;
#pragma unroll
    for (int j = 0; j < 4; ++j) {
      const int c0 = tn + wc + j * 16 + l15;
#pragma unroll
      for (int r = 0; r < 4; ++r)
        C[(long)(r0 + r) * 1024 + c0] = acc[i][j][r] + bvadd;
    }
  }
}

extern "C" void kernel_launch(void* const* d_in, const int* in_sizes, int n_in,
                              void* d_out, int out_size, void* d_ws,
                              size_t ws_size, hipStream_t stream) {
  const float* batch = (const float*)d_in[0];  // (8,1024,1024)
  const float* projL = (const float*)d_in[1];  // (1024,256)
  const float* projR = (const float*)d_in[2];  // (256,1024)
  const float* bias = (const float*)d_in[3];   // (1,)
  float* out = (float*)d_out;                  // (8,1024,1024)

  // workspace: Bcat (512x1024 bf16 = 1 MB) then LR (8192x512 bf16 = 8.4 MB)
  char* ws = (char*)d_ws;
  bf16_t* Bcat = (bf16_t*)ws;
  bf16_t* LR = (bf16_t*)(ws + (long)512 * 1024 * 2);

  // 1) Bcat: rows 0..255 = proj_L^T, rows 256..511 = proj_R (both bf16)
  prep_Bcat<<<512, 256, 0, stream>>>(projL, projR, Bcat);

  // 2) GEMM1: LR = batch @ Bcat^T (A direct-to-reg, B true-dbuf async16,
  //    one barrier per BK=128 step)
  gemm1_fusedA<<<512, 256, 0, stream>>>(batch, Bcat, LR);

  // 3) GEMM2: out[b] = left[b] @ right[b]^T + bias (128x128, dbuf)  [R1 form]
  gemm2<<<512, 256, 0, stream>>>(LR, out, bias);
}

// Round 8
// 130.615 us; speedup vs baseline: 1.0134x; 1.0134x over previous
//
#include <hip/hip_runtime.h>

typedef __bf16 bf16_t;
typedef __bf16 bf16x8 __attribute__((ext_vector_type(8)));
typedef __bf16 bf16x4 __attribute__((ext_vector_type(4)));
typedef float f32x4 __attribute__((ext_vector_type(4)));

__device__ __forceinline__ void async16(const void* g, void* l) {
  __builtin_amdgcn_global_load_lds(
      (const __attribute__((address_space(1))) unsigned int*)g,
      (__attribute__((address_space(3))) unsigned int*)l,
      16, 0, 0);
}

__device__ __forceinline__ bf16x8 cvt8(const float4 a, const float4 b) {
  bf16x8 v;
  v[0] = (bf16_t)a.x; v[1] = (bf16_t)a.y; v[2] = (bf16_t)a.z; v[3] = (bf16_t)a.w;
  v[4] = (bf16_t)b.x; v[5] = (bf16_t)b.y; v[6] = (bf16_t)b.z; v[7] = (bf16_t)b.w;
  return v;
}

// ---------------------------------------------------------------------------
// Fused prep for Bcat (512 x 1024 bf16)  [R1 known-good form]
// ---------------------------------------------------------------------------
__global__ void prep_Bcat(const float* __restrict__ projL,
                          const float* __restrict__ projR,
                          bf16_t* __restrict__ Bcat) {
  const int t = threadIdx.x;
  if (blockIdx.x < 256) {
    int i = blockIdx.x * 256 + t;
    float4 v = ((const float4*)projR)[i];
    bf16x4 o;
    o[0] = (bf16_t)v.x; o[1] = (bf16_t)v.y; o[2] = (bf16_t)v.z; o[3] = (bf16_t)v.w;
    ((bf16x4*)(Bcat + (long)256 * 1024))[i] = o;
  } else {
    __shared__ float tile[32][33];
    const int bb = blockIdx.x - 256;
    const int n0 = (bb & 7) * 32;   // col block in projL (N=256)
    const int k0 = (bb >> 3) * 32;  // row block in projL (K=1024)
    const int tx = t & 31;
    const int ty = t >> 5;  // 0..7
#pragma unroll
    for (int i = 0; i < 32; i += 8)
      tile[ty + i][tx] = projL[(long)(k0 + ty + i) * 256 + n0 + tx];
    __syncthreads();
#pragma unroll
    for (int i = 0; i < 32; i += 8)
      Bcat[(long)(n0 + ty + i) * 1024 + k0 + tx] = (bf16_t)tile[tx][ty + i];
  }
}

// ---------------------------------------------------------------------------
// GEMM1 — A direct-to-reg + T4 counted-vmcnt pipeline:
//   LR(8192x512 bf16) = batch(8192x1024 f32) @ Bcat(512x1024 bf16)^T
// 64x128 tile, 512 blocks -> 2 blocks/CU. BK=128, 8 steps, fully unrolled.
// R7 diagnosis: latency-bound (MfmaUtil 6%, HBM 10%, occ 16%) — A loads had
// zero prefetch distance; R1's variant lost to __syncthreads' vmcnt(0) drain.
// Fix (T4/m218): per step s issue B-async16(s+1)->dbuf then A-float4(s+1)->
// alternate reg set; compute step s; end with s_waitcnt vmcnt(8) (retires
// exactly the 8 B-asyncs: issue order pinned by sched_barrier(0)) + RAW
// s_barrier — so A(s+1) stays in flight ACROSS the barrier with a full step
// (~600+ cy) of cover, and B(s+1)'s LDS writes are retired by every wave
// before any wave reads them (race-safe: vmcnt retires in issue order).
// A fragment map (element-identical to the old LDS read): row tm+wr+i*16+l15,
// k k0+kc*32+quad*8; cvt fp32->bf16 in-reg (no As buffer, no ds_write/read).
// LDS: B dbuf 2 x 32 KB = 64 KB -> 2 blocks/CU. XCD swizzle: tm=bx&127.
// ---------------------------------------------------------------------------
__global__ __launch_bounds__(256, 2) void gemm1_fusedA(
    const float* __restrict__ batch, const bf16_t* __restrict__ Bcat,
    bf16_t* __restrict__ LR) {
  const int bx = blockIdx.x;
  const int tm = (bx & 127) * 64;  // M tile (8192/64 = 128)
  const int tn = (bx >> 7) * 128;  // N tile (512/128 = 4)

  // Bs[buf][kc][128][32] : per buf 4*4096 = 16384 elem (32 KB); 2 bufs.
  __shared__ __attribute__((aligned(16))) bf16_t Bs[2 * 16384];

  const int t = threadIdx.x;
  const int lane = t & 63;
  const int quad = lane >> 4;
  const int l15 = lane & 15;
  const int wave = t >> 6;
  const int wr = (wave >> 1) * 32;  // 0 / 32  (M)
  const int wc = (wave & 1) * 64;   // 0 / 64  (N)

  // B staging (legal async16 map): row rS=t>>2, 16B slot (t&3)*8;
  // dest = wave-uniform base + t*16B. Second async per kc: rows 64..127.
  const int rS = t >> 2;
  const int cS = (t & 3) * 8;
  const bf16_t* gB = Bcat + (long)(tn + rS) * 1024 + cS;

  // A direct-fragment base: row tm+wr+l15 (i adds 16 rows), col quad*8
  const float* gA = batch + (long)(tm + wr + l15) * 1024 + quad * 8;

  f32x4 acc[2][4];
#pragma unroll
  for (int i = 0; i < 2; ++i)
#pragma unroll
    for (int j = 0; j < 4; ++j)
      acc[i][j] = (f32x4){0.f, 0.f, 0.f, 0.f};

  // Two A register sets, statically indexed after full unroll (rule #20).
  float4 a0[2][4][2], a1[2][4][2];  // [set][kc][half]

  // ---- prologue: B(0) asyncs -> buf0, then A(0) loads -> set0 ----
#pragma unroll
  for (int kc = 0; kc < 4; ++kc) {
    async16(gB + kc * 32, Bs + kc * 4096 + t * 8);
    async16(gB + kc * 32 + (long)64 * 1024, Bs + kc * 4096 + 2048 + t * 8);
  }
  __builtin_amdgcn_sched_barrier(0);  // pin: B-asyncs issue before A-loads
#pragma unroll
  for (int kc = 0; kc < 4; ++kc) {
    const float* p0 = gA + kc * 32;
    a0[0][kc][0] = *(const float4*)p0;
    a0[0][kc][1] = *(const float4*)(p0 + 4);
    const float* p1 = p0 + (long)16 * 1024;
    a1[0][kc][0] = *(const float4*)p1;
    a1[0][kc][1] = *(const float4*)(p1 + 4);
  }
  asm volatile("s_waitcnt vmcnt(8)" ::: "memory");  // retire B(0) only
  __builtin_amdgcn_s_barrier();
  __builtin_amdgcn_sched_barrier(0);

#pragma unroll
  for (int s = 0; s < 8; ++s) {  // K=1024, BK=128
    const int cur = s & 1;
    const int nxt = cur ^ 1;
    const int k0 = s * 128;
    if (s < 7) {
      // B asyncs for s+1 -> other buffer (FIRST: oldest in vmcnt order)
#pragma unroll
      for (int kc = 0; kc < 4; ++kc) {
        async16(gB + k0 + 128 + kc * 32, Bs + nxt * 16384 + kc * 4096 + t * 8);
        async16(gB + k0 + 128 + kc * 32 + (long)64 * 1024,
                Bs + nxt * 16384 + kc * 4096 + 2048 + t * 8);
      }
      __builtin_amdgcn_sched_barrier(0);  // keep A-loads after B-asyncs
      // A loads for s+1 -> alternate reg set (ride through the barrier)
#pragma unroll
      for (int kc = 0; kc < 4; ++kc) {
        const float* p0 = gA + k0 + 128 + kc * 32;
        a0[nxt][kc][0] = *(const float4*)p0;
        a0[nxt][kc][1] = *(const float4*)(p0 + 4);
        const float* p1 = p0 + (long)16 * 1024;
        a1[nxt][kc][0] = *(const float4*)p1;
        a1[nxt][kc][1] = *(const float4*)(p1 + 4);
      }
    }
    // ---- compute step s: cvt A(s) (compiler waits its vmcnt) + MFMA ----
#pragma unroll
    for (int kc = 0; kc < 4; ++kc) {
      bf16x8 af[2], bv[4];
      af[0] = cvt8(a0[cur][kc][0], a0[cur][kc][1]);
      af[1] = cvt8(a1[cur][kc][0], a1[cur][kc][1]);
      const bf16_t* Bk = Bs + cur * 16384 + kc * 4096;
#pragma unroll
      for (int j = 0; j < 4; ++j)
        bv[j] = *(const bf16x8*)(Bk + (wc + j * 16 + l15) * 32 + quad * 8);
#pragma unroll
      for (int i = 0; i < 2; ++i)
#pragma unroll
        for (int j = 0; j < 4; ++j)
          acc[i][j] = __builtin_amdgcn_mfma_f32_16x16x32_bf16(af[i], bv[j],
                                                              acc[i][j], 0, 0, 0);
    }
    if (s < 7) {
      // retire B(s+1) asyncs (oldest 8 of the 16 outstanding), NOT A(s+1)
      asm volatile("s_waitcnt vmcnt(8)" ::: "memory");
      __builtin_amdgcn_s_barrier();   // raw: A(s+1) stays in flight
      __builtin_amdgcn_sched_barrier(0);
    }
  }

  // Epilogue -> LR bf16 (ldc=512). C/D: col = lane&15, row = quad*4 + reg
#pragma unroll
  for (int i = 0; i < 2; ++i) {
    const int r0 = tm + wr + i * 16 + quad * 4;
#pragma unroll
    for (int j = 0; j < 4; ++j) {
      const int c0 = tn + wc + j * 16 + l15;
#pragma unroll
      for (int r = 0; r < 4; ++r)
        LR[(long)(r0 + r) * 512 + c0] = (bf16_t)acc[i][j][r];
    }
  }
}

// ---------------------------------------------------------------------------
// GEMM2 [R1's known-good form]:
// out[b](1024x1024 f32) = left[b](1024x256) @ right[b](1024x256)^T + bias
// 128x128 tile; K=256 as BK=64 x 4 steps, double-buffered. LDS 64 KB ->
// 2 blocks/CU. BATCH-to-XCD pinning: b = bx&7.
// ---------------------------------------------------------------------------
__global__ __launch_bounds__(256, 2) void gemm2(const bf16_t* __restrict__ LR,
                                                float* __restrict__ out,
                                                const float* __restrict__ bias) {
  const int bx = blockIdx.x;
  const int bz = bx & 7;         // batch -> XCD
  const int tile = bx >> 3;      // 0..63
  const int tm = (tile & 7) * 128;   // row tile (i)
  const int tn = (tile >> 3) * 128;  // col tile (j)
  const bf16_t* LRb = LR + (long)bz * 1024 * 512;

  __shared__ __attribute__((aligned(16))) bf16_t As[2 * 8192];
  __shared__ __attribute__((aligned(16))) bf16_t Bs[2 * 8192];

  const int t = threadIdx.x;
  const int lane = t & 63;
  const int quad = lane >> 4;
  const int l15 = lane & 15;
  const int wave = t >> 6;
  const int wr = (wave >> 1) * 64;
  const int wc = (wave & 1) * 64;

  const int rS = t >> 2;          // 0..63
  const int cS = (t & 3) * 8;     // 0,8,16,24
  const bf16_t* gA = LRb + (long)(tm + rS) * 512 + cS;        // left
  const bf16_t* gB = LRb + (long)(tn + rS) * 512 + 256 + cS;  // right

  f32x4 acc[4][4];
#pragma unroll
  for (int i = 0; i < 4; ++i)
#pragma unroll
    for (int j = 0; j < 4; ++j)
      acc[i][j] = (f32x4){0.f, 0.f, 0.f, 0.f};

  auto STAGE = [&](int buf, int s) {
    const int k0 = s * 64;
    bf16_t* dA = As + buf * 8192 + t * 8;
    bf16_t* dB = Bs + buf * 8192 + t * 8;
#pragma unroll
    for (int kc = 0; kc < 2; ++kc) {
      const int ko = k0 + kc * 32;
      async16(gA + ko, dA + kc * 4096);
      async16(gA + ko + (long)64 * 512, dA + kc * 4096 + 2048);
      async16(gB + ko, dB + kc * 4096);
      async16(gB + ko + (long)64 * 512, dB + kc * 4096 + 2048);
    }
  };

  STAGE(0, 0);
  __syncthreads();  // drains prologue async16

#pragma unroll
  for (int s = 0; s < 4; ++s) {  // K=256, BK=64
    if (s < 3) STAGE((s + 1) & 1, s + 1);
    const bf16_t* Ab = As + (s & 1) * 8192;
    const bf16_t* Bb = Bs + (s & 1) * 8192;
#pragma unroll
    for (int kc = 0; kc < 2; ++kc) {
      const bf16_t* Ak = Ab + kc * 4096;
      const bf16_t* Bk = Bb + kc * 4096;
      bf16x8 af[4], bv[4];
#pragma unroll
      for (int i = 0; i < 4; ++i)
        af[i] = *(const bf16x8*)(Ak + (wr + i * 16 + l15) * 32 + quad * 8);
#pragma unroll
      for (int j = 0; j < 4; ++j)
        bv[j] = *(const bf16x8*)(Bk + (wc + j * 16 + l15) * 32 + quad * 8);
#pragma unroll
      for (int i = 0; i < 4; ++i)
#pragma unroll
        for (int j = 0; j < 4; ++j)
          acc[i][j] = __builtin_amdgcn_mfma_f32_16x16x32_bf16(af[i], bv[j],
                                                              acc[i][j], 0, 0, 0);
    }
    if (s < 3) __syncthreads();
  }

  float* C = out + (long)bz * 1024 * 1024;
  const float bvadd = bias[0];
#pragma unroll
  for (int i = 0; i < 4; ++i) {
    const int r0 = tm + wr + i * 16 + quad * 4;
#pragma unroll
    for (int j = 0; j < 4; ++j) {
      const int c0 = tn + wc + j * 16 + l15;
#pragma unroll
      for (int r = 0; r < 4; ++r)
        C[(long)(r0 + r) * 1024 + c0] = acc[i][j][r] + bvadd;
    }
  }
}

extern "C" void kernel_launch(void* const* d_in, const int* in_sizes, int n_in,
                              void* d_out, int out_size, void* d_ws,
                              size_t ws_size, hipStream_t stream) {
  const float* batch = (const float*)d_in[0];  // (8,1024,1024)
  const float* projL = (const float*)d_in[1];  // (1024,256)
  const float* projR = (const float*)d_in[2];  // (256,1024)
  const float* bias = (const float*)d_in[3];   // (1,)
  float* out = (float*)d_out;                  // (8,1024,1024)

  // workspace: Bcat (512x1024 bf16 = 1 MB) then LR (8192x512 bf16 = 8.4 MB)
  char* ws = (char*)d_ws;
  bf16_t* Bcat = (bf16_t*)ws;
  bf16_t* LR = (bf16_t*)(ws + (long)512 * 1024 * 2);

  // 1) Bcat: rows 0..255 = proj_L^T, rows 256..511 = proj_R (both bf16)
  prep_Bcat<<<512, 256, 0, stream>>>(projL, projR, Bcat);

  // 2) GEMM1: LR = batch @ Bcat^T (A direct-to-reg, counted-vmcnt pipeline)
  gemm1_fusedA<<<512, 256, 0, stream>>>(batch, Bcat, LR);

  // 3) GEMM2: out[b] = left[b] @ right[b]^T + bias (128x128, dbuf)  [R1 form]
  gemm2<<<512, 256, 0, stream>>>(LR, out, bias);
}

// Round 9
// 115.088 us; speedup vs baseline: 1.1501x; 1.1349x over previous
//
#include <hip/hip_runtime.h>

typedef __bf16 bf16_t;
typedef __bf16 bf16x8 __attribute__((ext_vector_type(8)));
typedef __bf16 bf16x4 __attribute__((ext_vector_type(4)));
typedef float f32x4 __attribute__((ext_vector_type(4)));

__device__ __forceinline__ void async16(const void* g, void* l) {
  __builtin_amdgcn_global_load_lds(
      (const __attribute__((address_space(1))) unsigned int*)g,
      (__attribute__((address_space(3))) unsigned int*)l,
      16, 0, 0);
}

__device__ __forceinline__ bf16x8 cvt8(const float4 a, const float4 b) {
  bf16x8 v;
  v[0] = (bf16_t)a.x; v[1] = (bf16_t)a.y; v[2] = (bf16_t)a.z; v[3] = (bf16_t)a.w;
  v[4] = (bf16_t)b.x; v[5] = (bf16_t)b.y; v[6] = (bf16_t)b.z; v[7] = (bf16_t)b.w;
  return v;
}

// ---------------------------------------------------------------------------
// Fused prep for Bcat (512 x 1024 bf16)  [R1 known-good form]
// ---------------------------------------------------------------------------
__global__ void prep_Bcat(const float* __restrict__ projL,
                          const float* __restrict__ projR,
                          bf16_t* __restrict__ Bcat) {
  const int t = threadIdx.x;
  if (blockIdx.x < 256) {
    int i = blockIdx.x * 256 + t;
    float4 v = ((const float4*)projR)[i];
    bf16x4 o;
    o[0] = (bf16_t)v.x; o[1] = (bf16_t)v.y; o[2] = (bf16_t)v.z; o[3] = (bf16_t)v.w;
    ((bf16x4*)(Bcat + (long)256 * 1024))[i] = o;
  } else {
    __shared__ float tile[32][33];
    const int bb = blockIdx.x - 256;
    const int n0 = (bb & 7) * 32;   // col block in projL (N=256)
    const int k0 = (bb >> 3) * 32;  // row block in projL (K=1024)
    const int tx = t & 31;
    const int ty = t >> 5;  // 0..7
#pragma unroll
    for (int i = 0; i < 32; i += 8)
      tile[ty + i][tx] = projL[(long)(k0 + ty + i) * 256 + n0 + tx];
    __syncthreads();
#pragma unroll
    for (int i = 0; i < 32; i += 8)
      Bcat[(long)(n0 + ty + i) * 1024 + k0 + tx] = (bf16_t)tile[tx][ty + i];
  }
}

// ---------------------------------------------------------------------------
// GEMM1 — HIGH-OCCUPANCY staged form:
//   LR(8192x512 bf16) = batch(8192x1024 f32) @ Bcat(512x1024 bf16)^T
// 32x128 tile -> 1024 blocks; LDS = A 8 KB + B 32 KB = 40 KB -> 4 blocks/CU
// (16 waves/CU, vs 2 blocks/8 waves before). m114: cross-block TLP is the
// barrier-drain-hiding mechanism — 4 resident blocks overlap each other's
// stage/drain phases, the thing R1's 2-block form lacked.
// A: COALESCED staging (R7/R8 lesson: direct per-fragment A loads scatter
// 16B/lane across 4KB-strided rows -> ~8x VMEM transactions -> invariant
// 45 us regardless of prefetch depth). Thread t loads 4 consecutive float4
// (row t>>3, cols (t&7)*16..+15; lanes 0-7 = 512B contiguous), cvt ->
// bf16x8 ds_write into [kc][32][32]. Reg-prefetch A(s+1) during compute.
// B: async16 (legal map: dest = uniform base + t*16B), [kc][128][32].
// Waves 1Mx4N: wave w owns cols w*32, acc[2][2] (32x32 per wave).
// Per BK=128 step: 16 MFMA + 16 ds_read_b128 per wave, 2 __syncthreads.
// XCD: tm = (bx&255)*32 -> the 4 N-sharers of an A row-tile are 256 apart
// (256%8==0 -> same XCD) -> A re-reads hit local L2.
// ---------------------------------------------------------------------------
__global__ __launch_bounds__(256, 4) void gemm1_fusedA(
    const float* __restrict__ batch, const bf16_t* __restrict__ Bcat,
    bf16_t* __restrict__ LR) {
  const int bx = blockIdx.x;
  const int tm = (bx & 255) * 32;  // M tile (8192/32 = 256)
  const int tn = (bx >> 8) * 128;  // N tile (512/128 = 4)

  __shared__ __attribute__((aligned(16))) bf16_t As[4096];   // [kc][32][32]
  __shared__ __attribute__((aligned(16))) bf16_t Bs[16384];  // [kc][128][32]

  const int t = threadIdx.x;
  const int lane = t & 63;
  const int quad = lane >> 4;
  const int l15 = lane & 15;
  const int w = t >> 6;  // wave 0..3 -> N columns w*32

  // B staging (legal async16 map): row rS=t>>2 (0..63), 16B slot (t&3)*8;
  // second async per kc covers rows 64..127 (+2048 elem).
  const int rS = t >> 2;
  const int cS = (t & 3) * 8;
  const bf16_t* gB = Bcat + (long)(tn + rS) * 1024 + cS;

  // A staging: row rA = t>>3 (0..31), cols cA=(t&7)*16 .. +15 (4 float4).
  const int rA = t >> 3;
  const int cA = (t & 7) * 16;
  const float* gA = batch + (long)(tm + rA) * 1024 + cA;
  // LDS dest: kc = cA>>5; col half (cA&31) in {0,16} (16-col chunk never
  // crosses a kc boundary).
  bf16_t* lA = As + (cA >> 5) * 1024 + rA * 32 + (cA & 31);

  f32x4 acc[2][2];
#pragma unroll
  for (int i = 0; i < 2; ++i)
#pragma unroll
    for (int j = 0; j < 2; ++j)
      acc[i][j] = (f32x4){0.f, 0.f, 0.f, 0.f};

  // A reg-prefetch buffer (cols cA..cA+15 of the current step)
  float4 f0, f1, f2, f3;
  f0 = *(const float4*)(gA + 0);
  f1 = *(const float4*)(gA + 4);
  f2 = *(const float4*)(gA + 8);
  f3 = *(const float4*)(gA + 12);

  for (int s = 0; s < 8; ++s) {  // K=1024, BK=128
    const int k0 = s * 128;
    // B asyncs for this step (L2-hot Bcat)
#pragma unroll
    for (int kc = 0; kc < 4; ++kc) {
      async16(gB + k0 + kc * 32, Bs + kc * 4096 + t * 8);
      async16(gB + k0 + kc * 32 + (long)64 * 1024,
              Bs + kc * 4096 + 2048 + t * 8);
    }
    // cvt + 2 ds_write_b128 of A(s) (f* loaded one step ago)
    *(bf16x8*)(lA) = cvt8(f0, f1);
    *(bf16x8*)(lA + 8) = cvt8(f2, f3);
    __syncthreads();  // drains B asyncs (vmcnt) + A ds_writes (lgkm)

    // reg-prefetch A(s+1): coalesced, rides under the MFMA block
    if (s < 7) {
      const float* p = gA + k0 + 128;
      f0 = *(const float4*)(p + 0);
      f1 = *(const float4*)(p + 4);
      f2 = *(const float4*)(p + 8);
      f3 = *(const float4*)(p + 12);
    }

#pragma unroll
    for (int kc = 0; kc < 4; ++kc) {
      const bf16_t* Ak = As + kc * 1024;
      const bf16_t* Bk = Bs + kc * 4096;
      bf16x8 af[2], bv[2];
#pragma unroll
      for (int i = 0; i < 2; ++i)
        af[i] = *(const bf16x8*)(Ak + (i * 16 + l15) * 32 + quad * 8);
#pragma unroll
      for (int j = 0; j < 2; ++j)
        bv[j] = *(const bf16x8*)(Bk + (w * 32 + j * 16 + l15) * 32 + quad * 8);
#pragma unroll
      for (int i = 0; i < 2; ++i)
#pragma unroll
        for (int j = 0; j < 2; ++j)
          acc[i][j] = __builtin_amdgcn_mfma_f32_16x16x32_bf16(af[i], bv[j],
                                                              acc[i][j], 0, 0, 0);
    }
    __syncthreads();  // protects As/Bs reuse next step
  }

  // Epilogue -> LR bf16 (ldc=512). C/D: col = lane&15, row = quad*4 + reg
#pragma unroll
  for (int i = 0; i < 2; ++i) {
    const int r0 = tm + i * 16 + quad * 4;
#pragma unroll
    for (int j = 0; j < 2; ++j) {
      const int c0 = tn + w * 32 + j * 16 + l15;
#pragma unroll
      for (int r = 0; r < 4; ++r)
        LR[(long)(r0 + r) * 512 + c0] = (bf16_t)acc[i][j][r];
    }
  }
}

// ---------------------------------------------------------------------------
// GEMM2 [R1's known-good form]:
// out[b](1024x1024 f32) = left[b](1024x256) @ right[b](1024x256)^T + bias
// 128x128 tile; K=256 as BK=64 x 4 steps, double-buffered. LDS 64 KB ->
// 2 blocks/CU. BATCH-to-XCD pinning: b = bx&7.
// ---------------------------------------------------------------------------
__global__ __launch_bounds__(256, 2) void gemm2(const bf16_t* __restrict__ LR,
                                                float* __restrict__ out,
                                                const float* __restrict__ bias) {
  const int bx = blockIdx.x;
  const int bz = bx & 7;         // batch -> XCD
  const int tile = bx >> 3;      // 0..63
  const int tm = (tile & 7) * 128;   // row tile (i)
  const int tn = (tile >> 3) * 128;  // col tile (j)
  const bf16_t* LRb = LR + (long)bz * 1024 * 512;

  __shared__ __attribute__((aligned(16))) bf16_t As[2 * 8192];
  __shared__ __attribute__((aligned(16))) bf16_t Bs[2 * 8192];

  const int t = threadIdx.x;
  const int lane = t & 63;
  const int quad = lane >> 4;
  const int l15 = lane & 15;
  const int wave = t >> 6;
  const int wr = (wave >> 1) * 64;
  const int wc = (wave & 1) * 64;

  const int rS = t >> 2;          // 0..63
  const int cS = (t & 3) * 8;     // 0,8,16,24
  const bf16_t* gA = LRb + (long)(tm + rS) * 512 + cS;        // left
  const bf16_t* gB = LRb + (long)(tn + rS) * 512 + 256 + cS;  // right

  f32x4 acc[4][4];
#pragma unroll
  for (int i = 0; i < 4; ++i)
#pragma unroll
    for (int j = 0; j < 4; ++j)
      acc[i][j] = (f32x4){0.f, 0.f, 0.f, 0.f};

  auto STAGE = [&](int buf, int s) {
    const int k0 = s * 64;
    bf16_t* dA = As + buf * 8192 + t * 8;
    bf16_t* dB = Bs + buf * 8192 + t * 8;
#pragma unroll
    for (int kc = 0; kc < 2; ++kc) {
      const int ko = k0 + kc * 32;
      async16(gA + ko, dA + kc * 4096);
      async16(gA + ko + (long)64 * 512, dA + kc * 4096 + 2048);
      async16(gB + ko, dB + kc * 4096);
      async16(gB + ko + (long)64 * 512, dB + kc * 4096 + 2048);
    }
  };

  STAGE(0, 0);
  __syncthreads();  // drains prologue async16

#pragma unroll
  for (int s = 0; s < 4; ++s) {  // K=256, BK=64
    if (s < 3) STAGE((s + 1) & 1, s + 1);
    const bf16_t* Ab = As + (s & 1) * 8192;
    const bf16_t* Bb = Bs + (s & 1) * 8192;
#pragma unroll
    for (int kc = 0; kc < 2; ++kc) {
      const bf16_t* Ak = Ab + kc * 4096;
      const bf16_t* Bk = Bb + kc * 4096;
      bf16x8 af[4], bv[4];
#pragma unroll
      for (int i = 0; i < 4; ++i)
        af[i] = *(const bf16x8*)(Ak + (wr + i * 16 + l15) * 32 + quad * 8);
#pragma unroll
      for (int j = 0; j < 4; ++j)
        bv[j] = *(const bf16x8*)(Bk + (wc + j * 16 + l15) * 32 + quad * 8);
#pragma unroll
      for (int i = 0; i < 4; ++i)
#pragma unroll
        for (int j = 0; j < 4; ++j)
          acc[i][j] = __builtin_amdgcn_mfma_f32_16x16x32_bf16(af[i], bv[j],
                                                              acc[i][j], 0, 0, 0);
    }
    if (s < 3) __syncthreads();
  }

  float* C = out + (long)bz * 1024 * 1024;
  const float bvadd = bias[0];
#pragma unroll
  for (int i = 0; i < 4; ++i) {
    const int r0 = tm + wr + i * 16 + quad * 4;
#pragma unroll
    for (int j = 0; j < 4; ++j) {
      const int c0 = tn + wc + j * 16 + l15;
#pragma unroll
      for (int r = 0; r < 4; ++r)
        C[(long)(r0 + r) * 1024 + c0] = acc[i][j][r] + bvadd;
    }
  }
}

extern "C" void kernel_launch(void* const* d_in, const int* in_sizes, int n_in,
                              void* d_out, int out_size, void* d_ws,
                              size_t ws_size, hipStream_t stream) {
  const float* batch = (const float*)d_in[0];  // (8,1024,1024)
  const float* projL = (const float*)d_in[1];  // (1024,256)
  const float* projR = (const float*)d_in[2];  // (256,1024)
  const float* bias = (const float*)d_in[3];   // (1,)
  float* out = (float*)d_out;                  // (8,1024,1024)

  // workspace: Bcat (512x1024 bf16 = 1 MB) then LR (8192x512 bf16 = 8.4 MB)
  char* ws = (char*)d_ws;
  bf16_t* Bcat = (bf16_t*)ws;
  bf16_t* LR = (bf16_t*)(ws + (long)512 * 1024 * 2);

  // 1) Bcat: rows 0..255 = proj_L^T, rows 256..511 = proj_R (both bf16)
  prep_Bcat<<<512, 256, 0, stream>>>(projL, projR, Bcat);

  // 2) GEMM1: LR = batch @ Bcat^T (32x128 tiles, 4 blocks/CU, coalesced
  //    staged A, async16 B)
  gemm1_fusedA<<<1024, 256, 0, stream>>>(batch, Bcat, LR);

  // 3) GEMM2: out[b] = left[b] @ right[b]^T + bias (128x128, dbuf)  [R1 form]
  gemm2<<<512, 256, 0, stream>>>(LR, out, bias);
}